// Round 2
// baseline (7801.569 us; speedup 1.0000x reference)
//
#include <hip/hip_runtime.h>

// HybridQLSTM: B=64, S=2048, D=4 (2x2 conv), H=256, NCLS=2.
// Design:
//  - prep_kernel: packs f16 weights (w_hh stream portion, w_ih, classifier) and
//    precomputes feat = sigmoid(x*cw+cb) as f16. Runs every launch (ws is re-poisoned).
//  - lstm_kernel: persistent, 1 block per batch (64 blocks x 1024 threads).
//    Thread t handles unit u=t>>2 over j-quarter kq=t&3 for all 4 gates (i,f,g,o).
//    i,f weight quarters live in VGPRs (64 VGPR); g,o quarters streamed from L2 each step.
//    dot via v_dot2_f32_f16; quad reduction via DPP (no LDS); h broadcast via 1KB LDS
//    (bank-staggered quarters), double-buffered -> ONE __syncthreads per step.
//  - cls_kernel: 16-rows-per-block f16 dot2 GEMM for the 2 ReLU layers + final linear.

#define BB 64
#define SS 2048
#define HH 256

typedef _Float16 f16;
typedef _Float16 h2 __attribute__((ext_vector_type(2)));
typedef _Float16 v8h __attribute__((ext_vector_type(8)));

union V8H { v8h v; h2 p[4]; };

__device__ __forceinline__ float fdot2f(h2 a, h2 b, float c){
#if __has_builtin(__builtin_amdgcn_fdot2)
  return __builtin_amdgcn_fdot2(a, b, c, false);
#else
  return c + (float)a.x*(float)b.x + (float)a.y*(float)b.y;
#endif
}

__device__ __forceinline__ float qsum4(float x){
#if __has_builtin(__builtin_amdgcn_mov_dpp)
  // quad_perm [1,0,3,2] = xor1 ; [2,3,0,1] = xor2
  x += __int_as_float(__builtin_amdgcn_mov_dpp(__float_as_int(x), 0xB1, 0xf, 0xf, true));
  x += __int_as_float(__builtin_amdgcn_mov_dpp(__float_as_int(x), 0x4E, 0xf, 0xf, true));
#else
  x += __shfl_xor(x, 1, 64);
  x += __shfl_xor(x, 2, 64);
#endif
  return x;
}

__device__ __forceinline__ float sigmf_(float x){ return 1.f/(1.f + __expf(-x)); }
__device__ __forceinline__ float tanhf_(float x){
  x = fminf(fmaxf(x, -15.f), 15.f);
  float e = __expf(2.f*x);
  return (e - 1.f)/(e + 1.f);
}
__device__ __forceinline__ h2 mkh2(float a, float b){ h2 r; r.x=(f16)a; r.y=(f16)b; return r; }

// ----------------------------------------------------------------------------
// prep: pack everything. Linear job space over one grid.
// seg0: feat (B*S = 131072), seg1: wstream (16384), seg2: wihp+biasp (1024),
// seg3: w1t (32768), seg4: w2t (32768), seg5: w3p (256). total 214272 = 837*256.
// ----------------------------------------------------------------------------
__global__ void prep_kernel(
    const float* __restrict__ x, const float* __restrict__ conv_w, const float* __restrict__ conv_b,
    const float* __restrict__ w_ih, const float* __restrict__ w_hh,
    const float* __restrict__ b_ih, const float* __restrict__ b_hh,
    const float* __restrict__ w1, const float* __restrict__ w2, const float* __restrict__ w3,
    f16* __restrict__ feat2, f16* __restrict__ wstream, f16* __restrict__ wihp,
    float* __restrict__ biasp, f16* __restrict__ w1t, f16* __restrict__ w2t, f16* __restrict__ w3p)
{
  int id = blockIdx.x*256 + threadIdx.x;
  if (id < BB*SS){
    float4 xv = *(const float4*)(x + (size_t)id*4);
    float f0 = sigmf_(xv.x*conv_w[0] + conv_b[0]);
    float f1 = sigmf_(xv.y*conv_w[1] + conv_b[1]);
    float f2 = sigmf_(xv.z*conv_w[2] + conv_b[2]);
    float f3 = sigmf_(xv.w*conv_w[3] + conv_b[3]);
    h2* o = (h2*)feat2 + (size_t)id*2;
    o[0] = mkh2(f0,f1); o[1] = mkh2(f2,f3);
    return;
  }
  id -= BB*SS;
  if (id < 16384){
    // wstream[c][t] = 8 f16 of w_hh[row][j0..j0+8), c<8 -> g-gate row, c>=8 -> o-gate row
    int c = id >> 10, t = id & 1023;
    int u = t >> 2, kq = t & 3;
    int row = u + ((c < 8) ? 512 : 768);
    int j0 = kq*64 + (c & 7)*8;
    const float* src = w_hh + (size_t)row*256 + j0;
    v8h o;
    #pragma unroll
    for (int j=0;j<8;j++) o[j] = (f16)src[j];
    *((v8h*)wstream + (size_t)c*1024 + t) = o;
    return;
  }
  id -= 16384;
  if (id < 1024){
    int u = id >> 2;
    f16* o = wihp + (size_t)id*16;
    float bb[4];
    #pragma unroll
    for (int i=0;i<4;i++){
      int row = u + 256*i;
      o[i*4+0] = (f16)w_ih[row*4+0];
      o[i*4+1] = (f16)w_ih[row*4+1];
      o[i*4+2] = (f16)w_ih[row*4+2];
      o[i*4+3] = (f16)w_ih[row*4+3];
      bb[i] = b_ih[row] + b_hh[row];
    }
    *(float4*)(biasp + (size_t)id*4) = make_float4(bb[0],bb[1],bb[2],bb[3]);
    return;
  }
  id -= 1024;
  if (id < 32768){ // w1t[kp*256+n] = half2(w1[n][2kp], w1[n][2kp+1])
    int kp = id >> 8, n = id & 255;
    w1t[(size_t)id*2+0] = (f16)w1[(size_t)n*256 + 2*kp];
    w1t[(size_t)id*2+1] = (f16)w1[(size_t)n*256 + 2*kp+1];
    return;
  }
  id -= 32768;
  if (id < 32768){
    int kp = id >> 8, n = id & 255;
    w2t[(size_t)id*2+0] = (f16)w2[(size_t)n*256 + 2*kp];
    w2t[(size_t)id*2+1] = (f16)w2[(size_t)n*256 + 2*kp+1];
    return;
  }
  id -= 32768;
  if (id < 256){
    int kp = id >> 1, cls = id & 1;
    w3p[(size_t)id*2+0] = (f16)w3[(size_t)cls*256 + 2*kp];
    w3p[(size_t)id*2+1] = (f16)w3[(size_t)cls*256 + 2*kp+1];
  }
}

// ----------------------------------------------------------------------------
// LSTM: 64 blocks x 1024 threads, one block per batch element.
// ----------------------------------------------------------------------------
__global__ __launch_bounds__(1024, 4) void lstm_kernel(
    const float* __restrict__ w_hh, const f16* __restrict__ feat2,
    const f16* __restrict__ wstream, const f16* __restrict__ wihp,
    const float* __restrict__ biasp, f16* __restrict__ hbuf)
{
  const int b = blockIdx.x, t = threadIdx.x;
  const int u = t >> 2, kq = t & 3;
  // h double buffer; quarters padded to 72 f16 (144B) to stagger banks across kq.
  __shared__ __align__(16) f16 hsh[2][4][72];

  // resident weights: gate rows u (i) and u+256 (f), this thread's j-quarter, as f16 pairs
  h2 wr0[32], wr1[32];
  {
    const float* s0 = w_hh + (size_t)u*256 + kq*64;
    const float* s1 = w_hh + (size_t)(u+256)*256 + kq*64;
    #pragma unroll
    for (int c=0;c<8;c++){
      float4 a = *(const float4*)(s0 + c*8);
      float4 q = *(const float4*)(s0 + c*8 + 4);
      wr0[c*4+0] = mkh2(a.x,a.y); wr0[c*4+1] = mkh2(a.z,a.w);
      wr0[c*4+2] = mkh2(q.x,q.y); wr0[c*4+3] = mkh2(q.z,q.w);
      a = *(const float4*)(s1 + c*8);
      q = *(const float4*)(s1 + c*8 + 4);
      wr1[c*4+0] = mkh2(a.x,a.y); wr1[c*4+1] = mkh2(a.z,a.w);
      wr1[c*4+2] = mkh2(q.x,q.y); wr1[c*4+3] = mkh2(q.z,q.w);
    }
  }
  h2 wx[8];
  {
    const h2* p = (const h2*)(wihp + (size_t)t*16);
    #pragma unroll
    for (int j=0;j<8;j++) wx[j] = p[j];
  }
  const float4 bsv = *(const float4*)(biasp + (size_t)t*4);

  if (t < 256) hsh[0][t>>6][t&63] = (f16)0.f;
  __syncthreads();

  const v8h* wsp = (const v8h*)wstream + t;           // + c*1024 per chunk
  const h2* fp = (const h2*)feat2 + (size_t)b*SS*2;
  f16* hrow = hbuf + (size_t)b*SS*HH;
  float cst = 0.f;
  int buf = 0;

  for (int s=0; s<SS; ++s){
    h2 f0 = fp[0], f1 = fp[1]; fp += 2;
    const v8h* hq = (const v8h*)(&hsh[buf][kq][0]);
    float a0=0.f, a1=0.f, a2=0.f, a3=0.f;
    #pragma unroll
    for (int c=0;c<8;c++){
      V8H hv; hv.v = hq[c];
      V8H wg; wg.v = wsp[(size_t)c*1024];
      V8H wo; wo.v = wsp[(size_t)(c+8)*1024];
      h2 p0 = hv.p[0], p1 = hv.p[1], p2 = hv.p[2], p3 = hv.p[3];
      a0 = fdot2f(wr0[c*4+0], p0, a0); a0 = fdot2f(wr0[c*4+1], p1, a0);
      a0 = fdot2f(wr0[c*4+2], p2, a0); a0 = fdot2f(wr0[c*4+3], p3, a0);
      a1 = fdot2f(wr1[c*4+0], p0, a1); a1 = fdot2f(wr1[c*4+1], p1, a1);
      a1 = fdot2f(wr1[c*4+2], p2, a1); a1 = fdot2f(wr1[c*4+3], p3, a1);
      a2 = fdot2f(wg.p[0], p0, a2); a2 = fdot2f(wg.p[1], p1, a2);
      a2 = fdot2f(wg.p[2], p2, a2); a2 = fdot2f(wg.p[3], p3, a2);
      a3 = fdot2f(wo.p[0], p0, a3); a3 = fdot2f(wo.p[1], p1, a3);
      a3 = fdot2f(wo.p[2], p2, a3); a3 = fdot2f(wo.p[3], p3, a3);
    }
    // reduce over the 4 j-quarters (lanes of the quad); result replicated in quad
    a0 = qsum4(a0); a1 = qsum4(a1); a2 = qsum4(a2); a3 = qsum4(a3);
    // add input projection + bias once (replicated, not summed)
    float gi = fdot2f(wx[1], f1, fdot2f(wx[0], f0, a0 + bsv.x));
    float gf = fdot2f(wx[3], f1, fdot2f(wx[2], f0, a1 + bsv.y));
    float gg = fdot2f(wx[5], f1, fdot2f(wx[4], f0, a2 + bsv.z));
    float go = fdot2f(wx[7], f1, fdot2f(wx[6], f0, a3 + bsv.w));
    float iv = sigmf_(gi), fv = sigmf_(gf), gv = tanhf_(gg), ov = sigmf_(go);
    cst = fv*cst + iv*gv;
    float hn = ov * tanhf_(cst);
    if (kq == 0){
      f16 hf = (f16)hn;
      hsh[buf^1][u>>6][u&63] = hf;
      hrow[u] = hf;
    }
    hrow += HH;
    __syncthreads();
    buf ^= 1;
  }
}

// ----------------------------------------------------------------------------
// classifier: 16 rows per 256-thread block; 4x4 register tile per thread.
// ----------------------------------------------------------------------------
__device__ __forceinline__ void fc_layer(const h2 (*src)[16], h2 (*dst)[16],
                                         const f16* __restrict__ wt,
                                         const float* __restrict__ bias, int t)
{
  const int rg = t >> 6;           // row group 0..3
  const int c0 = (t & 63) * 4;     // 4 output cols
  float acc[4][4];
  #pragma unroll
  for (int r=0;r<4;r++){ acc[r][0]=0.f; acc[r][1]=0.f; acc[r][2]=0.f; acc[r][3]=0.f; }
  #pragma unroll 4
  for (int kp=0; kp<128; kp++){
    V8H wv; wv.v = *(const v8h*)(wt + ((size_t)kp*256 + c0)*2);
    V8H rv; rv.v = *(const v8h*)(&src[kp][rg*4]);
    #pragma unroll
    for (int r=0;r<4;r++)
      #pragma unroll
      for (int c=0;c<4;c++)
        acc[r][c] = fdot2f(rv.p[r], wv.p[c], acc[r][c]);
  }
  const float4 bv = *(const float4*)(bias + c0);
  #pragma unroll
  for (int r=0;r<4;r++){
    float o0 = fmaxf(acc[r][0]+bv.x, 0.f);
    float o1 = fmaxf(acc[r][1]+bv.y, 0.f);
    float o2 = fmaxf(acc[r][2]+bv.z, 0.f);
    float o3 = fmaxf(acc[r][3]+bv.w, 0.f);
    dst[(c0>>1)  ][rg*4+r] = mkh2(o0,o1);
    dst[(c0>>1)+1][rg*4+r] = mkh2(o2,o3);
  }
}

__global__ __launch_bounds__(256) void cls_kernel(
    const f16* __restrict__ hbuf, const f16* __restrict__ w1t, const f16* __restrict__ w2t,
    const f16* __restrict__ w3p, const float* __restrict__ b1, const float* __restrict__ b2,
    const float* __restrict__ b3, float* __restrict__ out)
{
  __shared__ __align__(16) h2 rlA[128][16];
  __shared__ __align__(16) h2 rlB[128][16];
  const int t = threadIdx.x;
  const size_t R = (size_t)blockIdx.x * 16;
  {
    int r = t >> 4, seg = t & 15;
    const v8h* src = (const v8h*)(hbuf + (R + r)*HH + seg*16);
    V8H aH; aH.v = src[0];
    V8H bH; bH.v = src[1];
    int kp0 = seg*8;
    #pragma unroll
    for (int j=0;j<4;j++) rlA[kp0+j  ][r] = aH.p[j];
    #pragma unroll
    for (int j=0;j<4;j++) rlA[kp0+4+j][r] = bH.p[j];
  }
  __syncthreads();
  fc_layer(rlA, rlB, w1t, b1, t);
  __syncthreads();
  fc_layer(rlB, rlA, w2t, b2, t);
  __syncthreads();
  if (t < 32){
    int r = t >> 1, cls = t & 1;
    float acc = b3[cls];
    const h2* w3h = (const h2*)w3p;
    #pragma unroll 8
    for (int kp=0; kp<128; kp++)
      acc = fdot2f(rlA[kp][r], w3h[kp*2 + cls], acc);
    out[(R + r)*2 + cls] = acc;
  }
}

// ----------------------------------------------------------------------------
extern "C" void kernel_launch(void* const* d_in, const int* in_sizes, int n_in,
                              void* d_out, int out_size, void* d_ws, size_t ws_size,
                              hipStream_t stream) {
  const float* x      = (const float*)d_in[0];
  const float* conv_w = (const float*)d_in[1];
  const float* conv_b = (const float*)d_in[2];
  const float* w_ih   = (const float*)d_in[3];
  const float* w_hh   = (const float*)d_in[4];
  const float* b_ih   = (const float*)d_in[5];
  const float* b_hh   = (const float*)d_in[6];
  const float* w1     = (const float*)d_in[7];
  const float* b1     = (const float*)d_in[8];
  const float* w2     = (const float*)d_in[9];
  const float* b2     = (const float*)d_in[10];
  const float* w3     = (const float*)d_in[11];
  const float* b3     = (const float*)d_in[12];

  char* ws = (char*)d_ws;
  f16*   feat2   = (f16*)  (ws + 0x000000);  // 1 MB
  f16*   wstream = (f16*)  (ws + 0x100000);  // 256 KB
  f16*   wihp    = (f16*)  (ws + 0x140000);  // 32 KB
  float* biasp   = (float*)(ws + 0x148000);  // 16 KB
  f16*   w1t     = (f16*)  (ws + 0x14C000);  // 128 KB
  f16*   w2t     = (f16*)  (ws + 0x16C000);  // 128 KB
  f16*   w3p     = (f16*)  (ws + 0x18C000);  // 1 KB
  f16*   hbuf    = (f16*)  (ws + 0x190000);  // 64 MB

  prep_kernel<<<837, 256, 0, stream>>>(x, conv_w, conv_b, w_ih, w_hh, b_ih, b_hh,
                                       w1, w2, w3,
                                       feat2, wstream, wihp, biasp, w1t, w2t, w3p);
  lstm_kernel<<<BB, 1024, 0, stream>>>(w_hh, feat2, wstream, wihp, biasp, hbuf);
  cls_kernel<<<(BB*SS)/16, 256, 0, stream>>>(hbuf, w1t, w2t, w3p, b1, b2, b3, (float*)d_out);
}

// Round 3
// 4449.045 us; speedup vs baseline: 1.7535x; 1.7535x over previous
//
#include <hip/hip_runtime.h>

// HybridQLSTM: B=64, S=2048, D=4 (2x2 conv), H=256, NCLS=2.
// R2 design change vs R1: g-gate weights (128 KB f16) live in dynamic LDS
// (loaded once per block), o-gate streamed from L1/L2 (128 B/thread/step),
// i,f gates register-resident. This halves the per-step L1 stream (was 256 KB)
// and moves it to the independent LDS pipe.

#define BB 64
#define SS 2048
#define HH 256

typedef _Float16 f16;
typedef _Float16 h2 __attribute__((ext_vector_type(2)));
typedef _Float16 v8h __attribute__((ext_vector_type(8)));

union V8H { v8h v; h2 p[4]; };

__device__ __forceinline__ float fdot2f(h2 a, h2 b, float c){
#if __has_builtin(__builtin_amdgcn_fdot2)
  return __builtin_amdgcn_fdot2(a, b, c, false);
#else
  return c + (float)a.x*(float)b.x + (float)a.y*(float)b.y;
#endif
}

__device__ __forceinline__ float qsum4(float x){
#if __has_builtin(__builtin_amdgcn_mov_dpp)
  // quad_perm [1,0,3,2] = xor1 ; [2,3,0,1] = xor2
  x += __int_as_float(__builtin_amdgcn_mov_dpp(__float_as_int(x), 0xB1, 0xf, 0xf, true));
  x += __int_as_float(__builtin_amdgcn_mov_dpp(__float_as_int(x), 0x4E, 0xf, 0xf, true));
#else
  x += __shfl_xor(x, 1, 64);
  x += __shfl_xor(x, 2, 64);
#endif
  return x;
}

__device__ __forceinline__ float sigmf_(float x){ return 1.f/(1.f + __expf(-x)); }
__device__ __forceinline__ float tanhf_(float x){
  x = fminf(fmaxf(x, -15.f), 15.f);
  float e = __expf(2.f*x);
  return (e - 1.f)/(e + 1.f);
}
__device__ __forceinline__ h2 mkh2(float a, float b){ h2 r; r.x=(f16)a; r.y=(f16)b; return r; }

// ----------------------------------------------------------------------------
// prep: pack everything. Linear job space over one grid.
// seg0: feat (131072), seg1: wstream_o (8192), seg2: wihp+biasp (1024),
// seg3: w1t (32768), seg4: w2t (32768), seg5: w3p (256). total 206080 = 805*256.
// ----------------------------------------------------------------------------
__global__ void prep_kernel(
    const float* __restrict__ x, const float* __restrict__ conv_w, const float* __restrict__ conv_b,
    const float* __restrict__ w_ih, const float* __restrict__ w_hh,
    const float* __restrict__ b_ih, const float* __restrict__ b_hh,
    const float* __restrict__ w1, const float* __restrict__ w2, const float* __restrict__ w3,
    f16* __restrict__ feat2, f16* __restrict__ wstream, f16* __restrict__ wihp,
    float* __restrict__ biasp, f16* __restrict__ w1t, f16* __restrict__ w2t, f16* __restrict__ w3p)
{
  int id = blockIdx.x*256 + threadIdx.x;
  if (id < BB*SS){
    float4 xv = *(const float4*)(x + (size_t)id*4);
    float f0 = sigmf_(xv.x*conv_w[0] + conv_b[0]);
    float f1 = sigmf_(xv.y*conv_w[1] + conv_b[1]);
    float f2 = sigmf_(xv.z*conv_w[2] + conv_b[2]);
    float f3 = sigmf_(xv.w*conv_w[3] + conv_b[3]);
    h2* o = (h2*)feat2 + (size_t)id*2;
    o[0] = mkh2(f0,f1); o[1] = mkh2(f2,f3);
    return;
  }
  id -= BB*SS;
  if (id < 8192){
    // wstream[c][t] = 8 f16 of o-gate row (768+u), cols kq*64 + c*8 ..
    int c = id >> 10, t = id & 1023;
    int u = t >> 2, kq = t & 3;
    int row = 768 + u;
    int j0 = kq*64 + c*8;
    const float* src = w_hh + (size_t)row*256 + j0;
    v8h o;
    #pragma unroll
    for (int j=0;j<8;j++) o[j] = (f16)src[j];
    *((v8h*)wstream + (size_t)c*1024 + t) = o;
    return;
  }
  id -= 8192;
  if (id < 1024){
    int u = id >> 2;
    f16* o = wihp + (size_t)id*16;
    float bb[4];
    #pragma unroll
    for (int i=0;i<4;i++){
      int row = u + 256*i;
      o[i*4+0] = (f16)w_ih[row*4+0];
      o[i*4+1] = (f16)w_ih[row*4+1];
      o[i*4+2] = (f16)w_ih[row*4+2];
      o[i*4+3] = (f16)w_ih[row*4+3];
      bb[i] = b_ih[row] + b_hh[row];
    }
    *(float4*)(biasp + (size_t)id*4) = make_float4(bb[0],bb[1],bb[2],bb[3]);
    return;
  }
  id -= 1024;
  if (id < 32768){ // w1t[kp*256+n] = half2(w1[n][2kp], w1[n][2kp+1])
    int kp = id >> 8, n = id & 255;
    w1t[(size_t)id*2+0] = (f16)w1[(size_t)n*256 + 2*kp];
    w1t[(size_t)id*2+1] = (f16)w1[(size_t)n*256 + 2*kp+1];
    return;
  }
  id -= 32768;
  if (id < 32768){
    int kp = id >> 8, n = id & 255;
    w2t[(size_t)id*2+0] = (f16)w2[(size_t)n*256 + 2*kp];
    w2t[(size_t)id*2+1] = (f16)w2[(size_t)n*256 + 2*kp+1];
    return;
  }
  id -= 32768;
  if (id < 256){
    int kp = id >> 1, cls = id & 1;
    w3p[(size_t)id*2+0] = (f16)w3[(size_t)cls*256 + 2*kp];
    w3p[(size_t)id*2+1] = (f16)w3[(size_t)cls*256 + 2*kp+1];
  }
}

// ----------------------------------------------------------------------------
// LSTM: 64 blocks x 1024 threads, one block per batch element.
// Dynamic LDS: g-gate weights, 1024 segments (seg = thread) of 72 f16
// (64 data + 8 pad -> 36-word stride, 4-bank stagger).
// ----------------------------------------------------------------------------
#define GSEG 9   // v8h per segment (8 data + 1 pad)

__global__ __launch_bounds__(1024, 4) void lstm_kernel(
    const float* __restrict__ w_hh, const f16* __restrict__ feat2,
    const f16* __restrict__ wstream, const f16* __restrict__ wihp,
    const float* __restrict__ biasp, f16* __restrict__ hbuf)
{
  extern __shared__ __align__(16) f16 glds[];   // 1024*72 f16 = 147456 B
  const int b = blockIdx.x, t = threadIdx.x;
  const int u = t >> 2, kq = t & 3;
  // h double buffer; quarters padded to 72 f16 (144B) to stagger banks across kq.
  __shared__ __align__(16) f16 hsh[2][4][72];

  // resident weights: gate rows u (i) and u+256 (f), this thread's j-quarter, as f16 pairs
  h2 wr0[32], wr1[32];
  {
    const float* s0 = w_hh + (size_t)u*256 + kq*64;
    const float* s1 = w_hh + (size_t)(u+256)*256 + kq*64;
    #pragma unroll
    for (int c=0;c<8;c++){
      float4 a = *(const float4*)(s0 + c*8);
      float4 q = *(const float4*)(s0 + c*8 + 4);
      wr0[c*4+0] = mkh2(a.x,a.y); wr0[c*4+1] = mkh2(a.z,a.w);
      wr0[c*4+2] = mkh2(q.x,q.y); wr0[c*4+3] = mkh2(q.z,q.w);
      a = *(const float4*)(s1 + c*8);
      q = *(const float4*)(s1 + c*8 + 4);
      wr1[c*4+0] = mkh2(a.x,a.y); wr1[c*4+1] = mkh2(a.z,a.w);
      wr1[c*4+2] = mkh2(q.x,q.y); wr1[c*4+3] = mkh2(q.z,q.w);
    }
  }
  // g-gate weights -> LDS (rows 512+u, quarter kq), one-time
  {
    const float* gsrc = w_hh + (size_t)(512+u)*256 + kq*64;
    v8h* gdst = (v8h*)glds + (size_t)t*GSEG;
    #pragma unroll
    for (int c=0;c<8;c++){
      float4 a = *(const float4*)(gsrc + c*8);
      float4 q = *(const float4*)(gsrc + c*8 + 4);
      v8h o;
      o[0]=(f16)a.x; o[1]=(f16)a.y; o[2]=(f16)a.z; o[3]=(f16)a.w;
      o[4]=(f16)q.x; o[5]=(f16)q.y; o[6]=(f16)q.z; o[7]=(f16)q.w;
      gdst[c] = o;
    }
  }
  h2 wx[8];
  {
    const h2* p = (const h2*)(wihp + (size_t)t*16);
    #pragma unroll
    for (int j=0;j<8;j++) wx[j] = p[j];
  }
  const float4 bsv = *(const float4*)(biasp + (size_t)t*4);

  if (t < 256) hsh[0][t>>6][t&63] = (f16)0.f;
  __syncthreads();

  const v8h* wsp = (const v8h*)wstream + t;           // + c*1024 per chunk (o-gate)
  const v8h* gp  = (const v8h*)glds + (size_t)t*GSEG; // g-gate in LDS
  const h2* fp = (const h2*)feat2 + (size_t)b*SS*2;
  f16* hrow = hbuf + (size_t)b*SS*HH;
  float cst = 0.f;
  int buf = 0;

  for (int s=0; s<SS; ++s){
    h2 f0 = fp[0], f1 = fp[1]; fp += 2;
    const v8h* hq = (const v8h*)(&hsh[buf][kq][0]);
    float a0=0.f, a1=0.f, a2=0.f, a3=0.f;
    #pragma unroll
    for (int c=0;c<8;c++){
      V8H hv; hv.v = hq[c];
      V8H gv; gv.v = gp[c];
      V8H wo; wo.v = wsp[(size_t)c*1024];
      h2 p0 = hv.p[0], p1 = hv.p[1], p2 = hv.p[2], p3 = hv.p[3];
      a0 = fdot2f(wr0[c*4+0], p0, a0); a0 = fdot2f(wr0[c*4+1], p1, a0);
      a0 = fdot2f(wr0[c*4+2], p2, a0); a0 = fdot2f(wr0[c*4+3], p3, a0);
      a1 = fdot2f(wr1[c*4+0], p0, a1); a1 = fdot2f(wr1[c*4+1], p1, a1);
      a1 = fdot2f(wr1[c*4+2], p2, a1); a1 = fdot2f(wr1[c*4+3], p3, a1);
      a2 = fdot2f(gv.p[0], p0, a2); a2 = fdot2f(gv.p[1], p1, a2);
      a2 = fdot2f(gv.p[2], p2, a2); a2 = fdot2f(gv.p[3], p3, a2);
      a3 = fdot2f(wo.p[0], p0, a3); a3 = fdot2f(wo.p[1], p1, a3);
      a3 = fdot2f(wo.p[2], p2, a3); a3 = fdot2f(wo.p[3], p3, a3);
    }
    // reduce over the 4 j-quarters (lanes of the quad); result replicated in quad
    a0 = qsum4(a0); a1 = qsum4(a1); a2 = qsum4(a2); a3 = qsum4(a3);
    // add input projection + bias once (replicated, not summed)
    float gi = fdot2f(wx[1], f1, fdot2f(wx[0], f0, a0 + bsv.x));
    float gf = fdot2f(wx[3], f1, fdot2f(wx[2], f0, a1 + bsv.y));
    float gg = fdot2f(wx[5], f1, fdot2f(wx[4], f0, a2 + bsv.z));
    float go = fdot2f(wx[7], f1, fdot2f(wx[6], f0, a3 + bsv.w));
    float iv = sigmf_(gi), fv = sigmf_(gf), gv2 = tanhf_(gg), ov = sigmf_(go);
    cst = fv*cst + iv*gv2;
    float hn = ov * tanhf_(cst);
    if (kq == 0){
      f16 hf = (f16)hn;
      hsh[buf^1][u>>6][u&63] = hf;
      hrow[u] = hf;
    }
    hrow += HH;
    __syncthreads();
    buf ^= 1;
  }
}

// ----------------------------------------------------------------------------
// classifier: 16 rows per 256-thread block; 4x4 register tile per thread.
// ----------------------------------------------------------------------------
__device__ __forceinline__ void fc_layer(const h2 (*src)[16], h2 (*dst)[16],
                                         const f16* __restrict__ wt,
                                         const float* __restrict__ bias, int t)
{
  const int rg = t >> 6;           // row group 0..3
  const int c0 = (t & 63) * 4;     // 4 output cols
  float acc[4][4];
  #pragma unroll
  for (int r=0;r<4;r++){ acc[r][0]=0.f; acc[r][1]=0.f; acc[r][2]=0.f; acc[r][3]=0.f; }
  #pragma unroll 4
  for (int kp=0; kp<128; kp++){
    V8H wv; wv.v = *(const v8h*)(wt + ((size_t)kp*256 + c0)*2);
    V8H rv; rv.v = *(const v8h*)(&src[kp][rg*4]);
    #pragma unroll
    for (int r=0;r<4;r++)
      #pragma unroll
      for (int c=0;c<4;c++)
        acc[r][c] = fdot2f(rv.p[r], wv.p[c], acc[r][c]);
  }
  const float4 bv = *(const float4*)(bias + c0);
  #pragma unroll
  for (int r=0;r<4;r++){
    float o0 = fmaxf(acc[r][0]+bv.x, 0.f);
    float o1 = fmaxf(acc[r][1]+bv.y, 0.f);
    float o2 = fmaxf(acc[r][2]+bv.z, 0.f);
    float o3 = fmaxf(acc[r][3]+bv.w, 0.f);
    dst[(c0>>1)  ][rg*4+r] = mkh2(o0,o1);
    dst[(c0>>1)+1][rg*4+r] = mkh2(o2,o3);
  }
}

__global__ __launch_bounds__(256) void cls_kernel(
    const f16* __restrict__ hbuf, const f16* __restrict__ w1t, const f16* __restrict__ w2t,
    const f16* __restrict__ w3p, const float* __restrict__ b1, const float* __restrict__ b2,
    const float* __restrict__ b3, float* __restrict__ out)
{
  __shared__ __align__(16) h2 rlA[128][16];
  __shared__ __align__(16) h2 rlB[128][16];
  const int t = threadIdx.x;
  const size_t R = (size_t)blockIdx.x * 16;
  {
    int r = t >> 4, seg = t & 15;
    const v8h* src = (const v8h*)(hbuf + (R + r)*HH + seg*16);
    V8H aH; aH.v = src[0];
    V8H bH; bH.v = src[1];
    int kp0 = seg*8;
    #pragma unroll
    for (int j=0;j<4;j++) rlA[kp0+j  ][r] = aH.p[j];
    #pragma unroll
    for (int j=0;j<4;j++) rlA[kp0+4+j][r] = bH.p[j];
  }
  __syncthreads();
  fc_layer(rlA, rlB, w1t, b1, t);
  __syncthreads();
  fc_layer(rlB, rlA, w2t, b2, t);
  __syncthreads();
  if (t < 32){
    int r = t >> 1, cls = t & 1;
    float acc = b3[cls];
    const h2* w3h = (const h2*)w3p;
    #pragma unroll 8
    for (int kp=0; kp<128; kp++)
      acc = fdot2f(rlA[kp][r], w3h[kp*2 + cls], acc);
    out[(R + r)*2 + cls] = acc;
  }
}

// ----------------------------------------------------------------------------
extern "C" void kernel_launch(void* const* d_in, const int* in_sizes, int n_in,
                              void* d_out, int out_size, void* d_ws, size_t ws_size,
                              hipStream_t stream) {
  const float* x      = (const float*)d_in[0];
  const float* conv_w = (const float*)d_in[1];
  const float* conv_b = (const float*)d_in[2];
  const float* w_ih   = (const float*)d_in[3];
  const float* w_hh   = (const float*)d_in[4];
  const float* b_ih   = (const float*)d_in[5];
  const float* b_hh   = (const float*)d_in[6];
  const float* w1     = (const float*)d_in[7];
  const float* b1     = (const float*)d_in[8];
  const float* w2     = (const float*)d_in[9];
  const float* b2     = (const float*)d_in[10];
  const float* w3     = (const float*)d_in[11];
  const float* b3     = (const float*)d_in[12];

  char* ws = (char*)d_ws;
  f16*   feat2   = (f16*)  (ws + 0x000000);  // 1 MB
  f16*   wstream = (f16*)  (ws + 0x100000);  // 128 KB (o-gate)
  f16*   wihp    = (f16*)  (ws + 0x120000);  // 32 KB
  float* biasp   = (float*)(ws + 0x128000);  // 16 KB
  f16*   w1t     = (f16*)  (ws + 0x12C000);  // 128 KB
  f16*   w2t     = (f16*)  (ws + 0x14C000);  // 128 KB
  f16*   w3p     = (f16*)  (ws + 0x16C000);  // 1 KB
  f16*   hbuf    = (f16*)  (ws + 0x170000);  // 64 MB

  const int glds_bytes = 1024 * 72 * sizeof(f16);  // 147456
  (void)hipFuncSetAttribute((const void*)lstm_kernel,
                            hipFuncAttributeMaxDynamicSharedMemorySize, glds_bytes);

  prep_kernel<<<805, 256, 0, stream>>>(x, conv_w, conv_b, w_ih, w_hh, b_ih, b_hh,
                                       w1, w2, w3,
                                       feat2, wstream, wihp, biasp, w1t, w2t, w3p);
  lstm_kernel<<<BB, 1024, glds_bytes, stream>>>(w_hh, feat2, wstream, wihp, biasp, hbuf);
  cls_kernel<<<(BB*SS)/16, 256, 0, stream>>>(hbuf, w1t, w2t, w3p, b1, b2, b3, (float*)d_out);
}